// Round 1
// baseline (220.268 us; speedup 1.0000x reference)
//
#include <hip/hip_runtime.h>

// Problem constants (from reference)
constexpr int B     = 16384;
constexpr int NNEG  = 10;
constexpr int D     = 8;
constexpr int E     = 64;           // == wavefront size: lane l owns dim l
constexpr int ROWS  = B * (1 + NNEG);   // 180224; row id == output index

// One 64-lane wave per scoring row.
//   s_l  = sum_d  emb[x[d]][l]
//   ss_l = sum_d  emb[x[d]][l]^2
//   pair_sum = 0.5 * ( sum_l s_l^2  -  sum_l ss_l )     (= sum_{i<j} e_i . e_j)
//   score = exp(pair_sum * exp(pair_w[0]) + c)
__global__ __launch_bounds__(256) void APE_61555471286335_kernel(
    const int*   __restrict__ pos_x,   // [B, D]
    const int*   __restrict__ neg_x,   // [B, NNEG, D]
    const float* __restrict__ emb,     // [N_ENT, E]
    const float* __restrict__ pair_w,  // [N_PAIRS]
    const float* __restrict__ c,       // [1]
    float*       __restrict__ out)     // [ROWS] = pos[B] ++ neg[B*NNEG]
{
    const int wave = (int)((blockIdx.x * blockDim.x + threadIdx.x) >> 6);
    const int lane = threadIdx.x & 63;
    if (wave >= ROWS) return;

    // Row's index list: pos rows are the first B, neg rows follow in the same
    // flat order as the neg output region, so `wave` is also the out index.
    const int* idx = (wave < B) ? (pos_x + (size_t)wave * D)
                                : (neg_x + (size_t)(wave - B) * D);

    float s = 0.0f, ss = 0.0f;
#pragma unroll
    for (int d = 0; d < D; ++d) {
        const int id = idx[d];                        // wave-uniform (broadcast)
        const float v = emb[(size_t)id * E + lane];   // coalesced 256B per load
        s  += v;
        ss += v * v;
    }

    float a = s * s;
#pragma unroll
    for (int off = 32; off > 0; off >>= 1) {
        a  += __shfl_xor(a,  off, 64);
        ss += __shfl_xor(ss, off, 64);
    }

    if (lane == 0) {
        const float pair_sum = 0.5f * (a - ss);
        out[wave] = expf(pair_sum * expf(pair_w[0]) + c[0]);
    }
}

extern "C" void kernel_launch(void* const* d_in, const int* in_sizes, int n_in,
                              void* d_out, int out_size, void* d_ws, size_t ws_size,
                              hipStream_t stream) {
    const int*   pos_x  = (const int*)  d_in[0];
    const int*   neg_x  = (const int*)  d_in[1];
    const float* emb    = (const float*)d_in[2];
    const float* pair_w = (const float*)d_in[3];
    const float* c      = (const float*)d_in[4];
    float*       out    = (float*)      d_out;

    constexpr int BLOCK = 256;                 // 4 waves/block
    constexpr int WAVES_PER_BLOCK = BLOCK / 64;
    const int grid = (ROWS + WAVES_PER_BLOCK - 1) / WAVES_PER_BLOCK;  // 45056

    APE_61555471286335_kernel<<<grid, BLOCK, 0, stream>>>(
        pos_x, neg_x, emb, pair_w, c, out);
}